// Round 6
// baseline (89.886 us; speedup 1.0000x reference)
//
#include <hip/hip_runtime.h>

#define BATCH 8
#define CH 3
#define H_OUT 384
#define W_OUT 1280
#define H_IN 96
#define W_IN 320
#define HW_OUT (H_OUT * W_OUT)
#define HW_IN (H_IN * W_IN)

#define ROWS_PT 2                         // rows per thread (independent ILP chains)
#define SEGS_PER_ROW (W_OUT / 256)        // 5
#define PAIRS (H_OUT / ROWS_PT)           // 192
#define CHUNKS_PER_B (PAIRS * SEGS_PER_ROW)  // 960

#define LCOLS 68                          // staged cols per row (66 needed, pad)
#define LROWS 3                           // staged low-res rows
#define NSURF 4                           // disp, scene0, scene1, scene2

// 4-byte-aligned float2 for paired image taps (same cache line ~15/16).
struct __attribute__((packed, aligned(4))) f2 { float x, y; };

__global__ __launch_bounds__(256) void warp_sceneflow_kernel(
    const float* __restrict__ image,   // (B,3,384,1280)
    const float* __restrict__ disp,    // (B,1,96,320)
    const float* __restrict__ scene,   // (B,3,96,320)
    const float* __restrict__ intrin,  // (B,3,3)
    const float* __restrict__ aug,     // (B,2)
    float* __restrict__ out)           // (B,3,384,1280)
{
    // XCD-aware: b = bid&7 pins each batch's 5.9 MB image slice to one XCD L2.
    int bid = blockIdx.x;
    int b = bid & 7;
    int c = bid >> 3;                  // 0..959
    int yp = c / SEGS_PER_ROW;
    int xseg = c - yp * SEGS_PER_ROW;
    int x = xseg * 256 + threadIdx.x;  // wave lanes: 64 consecutive x
    int ybase = yp * ROWS_PT;

    // ---- LDS staging of the low-res maps (kills ~half the TA line-lookups) ----
    __shared__ float lds[NSURF][LROWS][LCOLS];

    // block-uniform staging window
    int ylo = (int)((float)ybase * ((float)(H_IN - 1) / (float)(H_OUT - 1)));
    int xlo = (int)((float)(xseg * 256) * ((float)(W_IN - 1) / (float)(W_OUT - 1)));

    {
        const float* surfp[NSURF] = {
            disp + b * HW_IN,
            scene + b * (CH * HW_IN),
            scene + b * (CH * HW_IN) + HW_IN,
            scene + b * (CH * HW_IN) + 2 * HW_IN };
        const int total = NSURF * LROWS * LCOLS;  // 816
        for (int i = threadIdx.x; i < total; i += 256) {
            int s = i / (LROWS * LCOLS);
            int rem = i - s * (LROWS * LCOLS);
            int row = rem / LCOLS;
            int col = rem - row * LCOLS;
            int gy = min(ylo + row, H_IN - 1);   // clamped: row j>=95-ylo replicates row 95
            int gx = min(xlo + col, W_IN - 1);   // clamped: col replicates col 319
            lds[s][row][col] = surfp[s][gy * W_IN + gx];
        }
    }
    __syncthreads();

    // per-batch scaled intrinsics (block-uniform)
    float sy = (float)H_OUT / aug[b * 2 + 0];
    float sxs = (float)W_OUT / aug[b * 2 + 1];
    float fx = intrin[b * 9 + 0] * sxs;
    float fy = intrin[b * 9 + 4] * sy;
    float cx = intrin[b * 9 + 2] * sxs;
    float cy = intrin[b * 9 + 5] * sy;
    float inv_fx = 1.0f / fx;
    float inv_fy = 1.0f / fy;

    // x-direction low-res interp (shared by both rows)
    float xsrc = (float)x * ((float)(W_IN - 1) / (float)(W_OUT - 1));
    int x0 = (int)xsrc;
    float wx = xsrc - (float)x0;
    int lx = x0 - xlo;                 // staged col; lx+1 always valid (clamp-replicated)

    const float* ib = image + b * (CH * HW_OUT);
    const float* im0 = ib;
    const float* im1 = ib + HW_OUT;
    const float* im2 = ib + 2 * HW_OUT;

    float g00[ROWS_PT], g01[ROWS_PT], g10[ROWS_PT], g11[ROWS_PT];
    int rb0[ROWS_PT], rb1[ROWS_PT];
    bool rc[ROWS_PT], lc[ROWS_PT];

    #pragma unroll
    for (int r = 0; r < ROWS_PT; ++r) {
        int y = ybase + r;

        float ysrc = (float)y * ((float)(H_IN - 1) / (float)(H_OUT - 1));
        int y0 = (int)ysrc;
        float wy = ysrc - (float)y0;
        int ly = y0 - ylo;             // 0 or 1; ly+1 always valid (clamp-replicated)

        // 16 LDS taps (off the TA pipe entirely)
        float d00 = lds[0][ly][lx],     d01 = lds[0][ly][lx + 1];
        float d10 = lds[0][ly + 1][lx], d11 = lds[0][ly + 1][lx + 1];
        float a00 = lds[1][ly][lx],     a01 = lds[1][ly][lx + 1];
        float a10 = lds[1][ly + 1][lx], a11 = lds[1][ly + 1][lx + 1];
        float b00 = lds[2][ly][lx],     b01 = lds[2][ly][lx + 1];
        float b10 = lds[2][ly + 1][lx], b11 = lds[2][ly + 1][lx + 1];
        float e00 = lds[3][ly][lx],     e01 = lds[3][ly][lx + 1];
        float e10 = lds[3][ly + 1][lx], e11 = lds[3][ly + 1][lx + 1];

        float w00 = (1.0f - wy) * (1.0f - wx);
        float w01 = (1.0f - wy) * wx;
        float w10 = wy * (1.0f - wx);
        float w11 = wy * wx;

        float dval = w00 * d00 + w01 * d01 + w10 * d10 + w11 * d11;
        float disp_full = dval * (float)W_OUT;
        float depth = fminf(fmaxf(fx * 0.54f / (disp_full + 1e-8f), 0.001f), 80.0f);

        float sc0 = w00 * a00 + w01 * a01 + w10 * a10 + w11 * a11;
        float sc1 = w00 * b00 + w01 * b01 + w10 * b10 + w11 * b11;
        float sc2 = w00 * e00 + w01 * e01 + w10 * e10 + w11 * e11;

        // backproject + scene flow + reproject
        float X = ((float)x - cx) * inv_fx * depth + sc0;
        float Y = ((float)y - cy) * inv_fy * depth + sc1;
        float Z = depth + sc2;
        float u = fx * X + cx * Z;
        float v = fy * Y + cy * Z;
        float rw = 1.0f / (Z + 1e-8f);
        float coord_x = u * rw;
        float coord_y = v * rw;

        // normalize round-trip (matches reference arithmetic)
        float nx = coord_x / (float)(W_OUT - 1) * 2.0f - 1.0f;
        float ny = coord_y / (float)(H_OUT - 1) * 2.0f - 1.0f;
        float gx = (nx + 1.0f) * 0.5f * (float)(W_OUT - 1);
        float gy = (ny + 1.0f) * 0.5f * (float)(H_OUT - 1);

        // grid sample weights/offsets, zeros padding
        float gx0f = floorf(gx), gy0f = floorf(gy);
        float fwx = gx - gx0f, fwy = gy - gy0f;
        int ix0 = (int)gx0f, iy0 = (int)gy0f;
        int ix1 = ix0 + 1, iy1 = iy0 + 1;
        bool vx0 = (ix0 >= 0) && (ix0 <= W_OUT - 1);
        bool vx1 = (ix1 >= 0) && (ix1 <= W_OUT - 1);
        bool vy0 = (iy0 >= 0) && (iy0 <= H_OUT - 1);
        bool vy1 = (iy1 >= 0) && (iy1 <= H_OUT - 1);
        int cx0 = min(max(ix0, 0), W_OUT - 1);
        int cx1 = min(max(ix1, 0), W_OUT - 1);
        int cy0 = min(max(iy0, 0), H_OUT - 1);
        int cy1 = min(max(iy1, 0), H_OUT - 1);
        g00[r] = (1.0f - fwy) * (1.0f - fwx) * ((vx0 && vy0) ? 1.0f : 0.0f);
        g01[r] = (1.0f - fwy) * fwx * ((vx1 && vy0) ? 1.0f : 0.0f);
        g10[r] = fwy * (1.0f - fwx) * ((vx0 && vy1) ? 1.0f : 0.0f);
        g11[r] = fwy * fwx * ((vx1 && vy1) ? 1.0f : 0.0f);

        // float2 gather bases: taps (x0,x1) merged into one dwordx2 per row
        int xbi = min(cx0, W_OUT - 2);
        rc[r] = (cx0 != xbi);     // right clamp: x0-tap is .y
        lc[r] = (cx1 == xbi);     // left clamp: x1-tap is .x
        rb0[r] = cy0 * W_OUT + xbi;
        rb1[r] = cy1 * W_OUT + xbi;
    }

    // 12 independent dwordx2 image gathers
    float res[ROWS_PT][CH];
    #pragma unroll
    for (int r = 0; r < ROWS_PT; ++r) {
        f2 P0 = *(const f2*)(im0 + rb0[r]); f2 P1 = *(const f2*)(im0 + rb1[r]);
        f2 Q0 = *(const f2*)(im1 + rb0[r]); f2 Q1 = *(const f2*)(im1 + rb1[r]);
        f2 T0 = *(const f2*)(im2 + rb0[r]); f2 T1 = *(const f2*)(im2 + rb1[r]);
        float p00 = rc[r] ? P0.y : P0.x, p01 = lc[r] ? P0.x : P0.y;
        float p10 = rc[r] ? P1.y : P1.x, p11 = lc[r] ? P1.x : P1.y;
        float q00 = rc[r] ? Q0.y : Q0.x, q01 = lc[r] ? Q0.x : Q0.y;
        float q10 = rc[r] ? Q1.y : Q1.x, q11 = lc[r] ? Q1.x : Q1.y;
        float t00 = rc[r] ? T0.y : T0.x, t01 = lc[r] ? T0.x : T0.y;
        float t10 = rc[r] ? T1.y : T1.x, t11 = lc[r] ? T1.x : T1.y;
        res[r][0] = g00[r] * p00 + g01[r] * p01 + g10[r] * p10 + g11[r] * p11;
        res[r][1] = g00[r] * q00 + g01[r] * q01 + g10[r] * q10 + g11[r] * q11;
        res[r][2] = g00[r] * t00 + g01[r] * t01 + g10[r] * t10 + g11[r] * t11;
    }

    float* ob = out + b * (CH * HW_OUT);
    #pragma unroll
    for (int r = 0; r < ROWS_PT; ++r) {
        int op = (ybase + r) * W_OUT + x;
        __builtin_nontemporal_store(res[r][0], ob + op);
        __builtin_nontemporal_store(res[r][1], ob + HW_OUT + op);
        __builtin_nontemporal_store(res[r][2], ob + 2 * HW_OUT + op);
    }
}

extern "C" void kernel_launch(void* const* d_in, const int* in_sizes, int n_in,
                              void* d_out, int out_size, void* d_ws, size_t ws_size,
                              hipStream_t stream) {
    const float* image  = (const float*)d_in[0];
    const float* disp   = (const float*)d_in[1];
    const float* scene  = (const float*)d_in[2];
    const float* intrin = (const float*)d_in[3];
    const float* aug    = (const float*)d_in[4];
    float* out = (float*)d_out;

    const int grid = BATCH * CHUNKS_PER_B;  // 7680 blocks
    warp_sceneflow_kernel<<<grid, 256, 0, stream>>>(image, disp, scene, intrin, aug, out);
}

// Round 7
// 58.210 us; speedup vs baseline: 1.5442x; 1.5442x over previous
//
#include <hip/hip_runtime.h>
#include <hip/hip_fp16.h>

#define BATCH 8
#define CH 3
#define H_OUT 384
#define W_OUT 1280
#define H_IN 96
#define W_IN 320
#define HW_OUT (H_OUT * W_OUT)
#define HW_IN (H_IN * W_IN)

#define ROWS_PT 2
#define SEGS_PER_ROW (W_OUT / 256)           // 5
#define PAIRS (H_OUT / ROWS_PT)              // 192
#define CHUNKS_PER_B (PAIRS * SEGS_PER_ROW)  // 960

#define LCOLS 68
#define LROWS 3
#define NSURF 4

// packed image: (B, H, W) x 4 fp16 {c0,c1,c2,0} = 8 B/pixel
#define PK_HALves 4
#define PK_BYTES ((size_t)BATCH * HW_OUT * 8)

struct __attribute__((packed, aligned(4))) f2 { float x, y; };
struct __attribute__((packed, aligned(8))) h8 { unsigned int w[4]; };  // 16B, 8B-aligned

// ---------------- pack pass: planar f32 -> interleaved fp16x4 ----------------
__global__ __launch_bounds__(256) void pack_kernel(
    const float* __restrict__ image, __half* __restrict__ pk)
{
    int i = blockIdx.x * 256 + threadIdx.x;       // exact: B*HW_OUT = 15360*256
    int b = i / HW_OUT;
    int p = i - b * HW_OUT;
    const float* ib = image + (size_t)b * (CH * HW_OUT) + p;
    float c0 = ib[0];
    float c1 = ib[HW_OUT];
    float c2 = ib[2 * HW_OUT];
    __half2 lo = __floats2half2_rn(c0, c1);
    __half2 hi = __floats2half2_rn(c2, 0.0f);
    uint2 v;
    v.x = *reinterpret_cast<unsigned int*>(&lo);
    v.y = *reinterpret_cast<unsigned int*>(&hi);
    *reinterpret_cast<uint2*>(pk + (size_t)i * 4) = v;
}

// ---------------- main kernel (templated: packed-fp16 or planar-f32 gathers) ----------------
template <bool PACKED>
__global__ __launch_bounds__(256) void warp_sceneflow_kernel(
    const float* __restrict__ image,
    const __half* __restrict__ pk,
    const float* __restrict__ disp,
    const float* __restrict__ scene,
    const float* __restrict__ intrin,
    const float* __restrict__ aug,
    float* __restrict__ out)
{
    int bid = blockIdx.x;
    int b = bid & 7;                   // XCD-pinned batch
    int c = bid >> 3;
    int yp = c / SEGS_PER_ROW;
    int xseg = c - yp * SEGS_PER_ROW;
    int x = xseg * 256 + threadIdx.x;
    int ybase = yp * ROWS_PT;

    __shared__ float lds[NSURF][LROWS][LCOLS];
    int ylo = (int)((float)ybase * ((float)(H_IN - 1) / (float)(H_OUT - 1)));
    int xlo = (int)((float)(xseg * 256) * ((float)(W_IN - 1) / (float)(W_OUT - 1)));
    {
        const float* surfp[NSURF] = {
            disp + b * HW_IN,
            scene + b * (CH * HW_IN),
            scene + b * (CH * HW_IN) + HW_IN,
            scene + b * (CH * HW_IN) + 2 * HW_IN };
        const int total = NSURF * LROWS * LCOLS;
        for (int i = threadIdx.x; i < total; i += 256) {
            int s = i / (LROWS * LCOLS);
            int rem = i - s * (LROWS * LCOLS);
            int row = rem / LCOLS;
            int col = rem - row * LCOLS;
            int gy = min(ylo + row, H_IN - 1);
            int gx = min(xlo + col, W_IN - 1);
            lds[s][row][col] = surfp[s][gy * W_IN + gx];
        }
    }
    __syncthreads();

    float sy = (float)H_OUT / aug[b * 2 + 0];
    float sxs = (float)W_OUT / aug[b * 2 + 1];
    float fx = intrin[b * 9 + 0] * sxs;
    float fy = intrin[b * 9 + 4] * sy;
    float cx = intrin[b * 9 + 2] * sxs;
    float cy = intrin[b * 9 + 5] * sy;
    float inv_fx = 1.0f / fx;
    float inv_fy = 1.0f / fy;

    float xsrc = (float)x * ((float)(W_IN - 1) / (float)(W_OUT - 1));
    int x0 = (int)xsrc;
    float wx = xsrc - (float)x0;
    int lx = x0 - xlo;

    float g00[ROWS_PT], g01[ROWS_PT], g10[ROWS_PT], g11[ROWS_PT];
    int rb0[ROWS_PT], rb1[ROWS_PT];
    bool rc[ROWS_PT], lc[ROWS_PT];

    #pragma unroll
    for (int r = 0; r < ROWS_PT; ++r) {
        int y = ybase + r;
        float ysrc = (float)y * ((float)(H_IN - 1) / (float)(H_OUT - 1));
        int y0 = (int)ysrc;
        float wy = ysrc - (float)y0;
        int ly = y0 - ylo;

        float d00 = lds[0][ly][lx],     d01 = lds[0][ly][lx + 1];
        float d10 = lds[0][ly + 1][lx], d11 = lds[0][ly + 1][lx + 1];
        float a00 = lds[1][ly][lx],     a01 = lds[1][ly][lx + 1];
        float a10 = lds[1][ly + 1][lx], a11 = lds[1][ly + 1][lx + 1];
        float b00 = lds[2][ly][lx],     b01 = lds[2][ly][lx + 1];
        float b10 = lds[2][ly + 1][lx], b11 = lds[2][ly + 1][lx + 1];
        float e00 = lds[3][ly][lx],     e01 = lds[3][ly][lx + 1];
        float e10 = lds[3][ly + 1][lx], e11 = lds[3][ly + 1][lx + 1];

        float w00 = (1.0f - wy) * (1.0f - wx);
        float w01 = (1.0f - wy) * wx;
        float w10 = wy * (1.0f - wx);
        float w11 = wy * wx;

        float dval = w00 * d00 + w01 * d01 + w10 * d10 + w11 * d11;
        float disp_full = dval * (float)W_OUT;
        float depth = fminf(fmaxf(fx * 0.54f / (disp_full + 1e-8f), 0.001f), 80.0f);

        float sc0 = w00 * a00 + w01 * a01 + w10 * a10 + w11 * a11;
        float sc1 = w00 * b00 + w01 * b01 + w10 * b10 + w11 * b11;
        float sc2 = w00 * e00 + w01 * e01 + w10 * e10 + w11 * e11;

        float X = ((float)x - cx) * inv_fx * depth + sc0;
        float Y = ((float)y - cy) * inv_fy * depth + sc1;
        float Z = depth + sc2;
        float u = fx * X + cx * Z;
        float v = fy * Y + cy * Z;
        float rw = 1.0f / (Z + 1e-8f);
        float coord_x = u * rw;
        float coord_y = v * rw;

        float nx = coord_x / (float)(W_OUT - 1) * 2.0f - 1.0f;
        float ny = coord_y / (float)(H_OUT - 1) * 2.0f - 1.0f;
        float gx = (nx + 1.0f) * 0.5f * (float)(W_OUT - 1);
        float gy = (ny + 1.0f) * 0.5f * (float)(H_OUT - 1);

        float gx0f = floorf(gx), gy0f = floorf(gy);
        float fwx = gx - gx0f, fwy = gy - gy0f;
        int ix0 = (int)gx0f, iy0 = (int)gy0f;
        int ix1 = ix0 + 1, iy1 = iy0 + 1;
        bool vx0 = (ix0 >= 0) && (ix0 <= W_OUT - 1);
        bool vx1 = (ix1 >= 0) && (ix1 <= W_OUT - 1);
        bool vy0 = (iy0 >= 0) && (iy0 <= H_OUT - 1);
        bool vy1 = (iy1 >= 0) && (iy1 <= H_OUT - 1);
        int cx0 = min(max(ix0, 0), W_OUT - 1);
        int cx1 = min(max(ix1, 0), W_OUT - 1);
        int cy0 = min(max(iy0, 0), H_OUT - 1);
        int cy1 = min(max(iy1, 0), H_OUT - 1);
        g00[r] = (1.0f - fwy) * (1.0f - fwx) * ((vx0 && vy0) ? 1.0f : 0.0f);
        g01[r] = (1.0f - fwy) * fwx * ((vx1 && vy0) ? 1.0f : 0.0f);
        g10[r] = fwy * (1.0f - fwx) * ((vx0 && vy1) ? 1.0f : 0.0f);
        g11[r] = fwy * fwx * ((vx1 && vy1) ? 1.0f : 0.0f);

        int xbi = min(cx0, W_OUT - 2);
        rc[r] = (cx0 != xbi);
        lc[r] = (cx1 == xbi);
        rb0[r] = cy0 * W_OUT + xbi;
        rb1[r] = cy1 * W_OUT + xbi;
    }

    float res[ROWS_PT][CH];
    if constexpr (PACKED) {
        const __half* pb = pk + (size_t)b * HW_OUT * 4;
        #pragma unroll
        for (int r = 0; r < ROWS_PT; ++r) {
            // one 16B load per tap-row covers both x-taps, all 3 channels
            h8 L0 = *reinterpret_cast<const h8*>(pb + (size_t)rb0[r] * 4);
            h8 L1 = *reinterpret_cast<const h8*>(pb + (size_t)rb1[r] * 4);
            unsigned t0a = rc[r] ? L0.w[2] : L0.w[0];  // x0-tap c0c1, row y0
            unsigned t0b = rc[r] ? L0.w[3] : L0.w[1];  // x0-tap c2,   row y0
            unsigned t1a = lc[r] ? L0.w[0] : L0.w[2];  // x1-tap c0c1, row y0
            unsigned t1b = lc[r] ? L0.w[1] : L0.w[3];
            unsigned u0a = rc[r] ? L1.w[2] : L1.w[0];  // row y1
            unsigned u0b = rc[r] ? L1.w[3] : L1.w[1];
            unsigned u1a = lc[r] ? L1.w[0] : L1.w[2];
            unsigned u1b = lc[r] ? L1.w[1] : L1.w[3];
            __half2 h0a = *reinterpret_cast<__half2*>(&t0a);
            __half2 h1a = *reinterpret_cast<__half2*>(&t1a);
            __half2 k0a = *reinterpret_cast<__half2*>(&u0a);
            __half2 k1a = *reinterpret_cast<__half2*>(&u1a);
            __half2 h0b = *reinterpret_cast<__half2*>(&t0b);
            __half2 h1b = *reinterpret_cast<__half2*>(&t1b);
            __half2 k0b = *reinterpret_cast<__half2*>(&u0b);
            __half2 k1b = *reinterpret_cast<__half2*>(&u1b);
            // channel 0
            res[r][0] = g00[r] * __low2float(h0a) + g01[r] * __low2float(h1a)
                      + g10[r] * __low2float(k0a) + g11[r] * __low2float(k1a);
            // channel 1
            res[r][1] = g00[r] * __high2float(h0a) + g01[r] * __high2float(h1a)
                      + g10[r] * __high2float(k0a) + g11[r] * __high2float(k1a);
            // channel 2
            res[r][2] = g00[r] * __low2float(h0b) + g01[r] * __low2float(h1b)
                      + g10[r] * __low2float(k0b) + g11[r] * __low2float(k1b);
        }
    } else {
        const float* ib = image + (size_t)b * (CH * HW_OUT);
        const float* im0 = ib;
        const float* im1 = ib + HW_OUT;
        const float* im2 = ib + 2 * HW_OUT;
        #pragma unroll
        for (int r = 0; r < ROWS_PT; ++r) {
            f2 P0 = *(const f2*)(im0 + rb0[r]); f2 P1 = *(const f2*)(im0 + rb1[r]);
            f2 Q0 = *(const f2*)(im1 + rb0[r]); f2 Q1 = *(const f2*)(im1 + rb1[r]);
            f2 T0 = *(const f2*)(im2 + rb0[r]); f2 T1 = *(const f2*)(im2 + rb1[r]);
            float p00 = rc[r] ? P0.y : P0.x, p01 = lc[r] ? P0.x : P0.y;
            float p10 = rc[r] ? P1.y : P1.x, p11 = lc[r] ? P1.x : P1.y;
            float q00 = rc[r] ? Q0.y : Q0.x, q01 = lc[r] ? Q0.x : Q0.y;
            float q10 = rc[r] ? Q1.y : Q1.x, q11 = lc[r] ? Q1.x : Q1.y;
            float t00 = rc[r] ? T0.y : T0.x, t01 = lc[r] ? T0.x : T0.y;
            float t10 = rc[r] ? T1.y : T1.x, t11 = lc[r] ? T1.x : T1.y;
            res[r][0] = g00[r] * p00 + g01[r] * p01 + g10[r] * p10 + g11[r] * p11;
            res[r][1] = g00[r] * q00 + g01[r] * q01 + g10[r] * q10 + g11[r] * q11;
            res[r][2] = g00[r] * t00 + g01[r] * t01 + g10[r] * t10 + g11[r] * t11;
        }
    }

    float* ob = out + (size_t)b * (CH * HW_OUT);
    #pragma unroll
    for (int r = 0; r < ROWS_PT; ++r) {
        int op = (ybase + r) * W_OUT + x;
        __builtin_nontemporal_store(res[r][0], ob + op);
        __builtin_nontemporal_store(res[r][1], ob + HW_OUT + op);
        __builtin_nontemporal_store(res[r][2], ob + 2 * HW_OUT + op);
    }
}

extern "C" void kernel_launch(void* const* d_in, const int* in_sizes, int n_in,
                              void* d_out, int out_size, void* d_ws, size_t ws_size,
                              hipStream_t stream) {
    const float* image  = (const float*)d_in[0];
    const float* disp   = (const float*)d_in[1];
    const float* scene  = (const float*)d_in[2];
    const float* intrin = (const float*)d_in[3];
    const float* aug    = (const float*)d_in[4];
    float* out = (float*)d_out;

    const int grid = BATCH * CHUNKS_PER_B;  // 7680 blocks

    if (ws_size >= PK_BYTES) {
        __half* pk = (__half*)d_ws;
        pack_kernel<<<BATCH * HW_OUT / 256, 256, 0, stream>>>(image, pk);
        warp_sceneflow_kernel<true><<<grid, 256, 0, stream>>>(
            image, pk, disp, scene, intrin, aug, out);
    } else {
        warp_sceneflow_kernel<false><<<grid, 256, 0, stream>>>(
            image, nullptr, disp, scene, intrin, aug, out);
    }
}

// Round 8
// 54.661 us; speedup vs baseline: 1.6444x; 1.0649x over previous
//
#include <hip/hip_runtime.h>
#include <hip/hip_fp16.h>

#define BATCH 8
#define CH 3
#define H_OUT 384
#define W_OUT 1280
#define H_IN 96
#define W_IN 320
#define HW_OUT (H_OUT * W_OUT)
#define HW_IN (H_IN * W_IN)

#define ROWS_PT 2
#define SEGS_PER_ROW (W_OUT / 256)           // 5
#define PAIRS (H_OUT / ROWS_PT)              // 192
#define CHUNKS_PER_B (PAIRS * SEGS_PER_ROW)  // 960

#define LCOLS 68
#define LROWS 3

// packed image: stride-1282 rows of fp16x4 {c0,c1,c2,0}, 8 B/pixel,
// +1-pixel front pad (allows base = -1), ghost cols 1280/1281 zeroed.
#define PSTRIDE 1282
#define PK_HALVES ((size_t)(1 + (size_t)BATCH * H_OUT * PSTRIDE) * 4)
#define PK_BYTES (PK_HALVES * 2)

struct __attribute__((packed, aligned(4))) f2 { float x, y; };
struct __attribute__((packed, aligned(8))) h8 { unsigned int w[4]; };  // 16B payload, 8B-aligned

// ---------------- pack pass: planar f32 -> strided interleaved fp16x4 ----------------
__global__ __launch_bounds__(256) void pack_kernel(
    const float* __restrict__ image, __half* __restrict__ pk)
{
    int i = blockIdx.x * 256 + threadIdx.x;       // B*HW_OUT threads exactly
    int b = i / HW_OUT;
    int p = i - b * HW_OUT;
    int y = p / W_OUT;
    int x = p - y * W_OUT;
    const float* ib = image + (size_t)b * (CH * HW_OUT) + p;
    float c0 = ib[0];
    float c1 = ib[HW_OUT];
    float c2 = ib[2 * HW_OUT];
    __half2 lo = __floats2half2_rn(c0, c1);
    __half2 hi = __floats2half2_rn(c2, 0.0f);
    uint2 v;
    v.x = *reinterpret_cast<unsigned int*>(&lo);
    v.y = *reinterpret_cast<unsigned int*>(&hi);
    __half* pd = pk + 4;  // data base (front pad = 1 pixel)
    size_t row = (size_t)b * H_OUT + y;
    *reinterpret_cast<uint2*>(pd + (row * PSTRIDE + x) * 4) = v;

    // pad maintenance: ghost cols per row + front pad pixel
    if (i < BATCH * H_OUT) {
        uint2 z; z.x = 0u; z.y = 0u;
        size_t r = (size_t)i;
        *reinterpret_cast<uint2*>(pd + (r * PSTRIDE + 1280) * 4) = z;
        *reinterpret_cast<uint2*>(pd + (r * PSTRIDE + 1281) * 4) = z;
        if (i == 0) *reinterpret_cast<uint2*>(pk) = z;
    }
}

// ---------------- main kernel ----------------
template <bool PACKED>
__global__ __launch_bounds__(256) void warp_sceneflow_kernel(
    const float* __restrict__ image,
    const __half* __restrict__ pk,
    const float* __restrict__ disp,
    const float* __restrict__ scene,
    const float* __restrict__ intrin,
    const float* __restrict__ aug,
    float* __restrict__ out)
{
    int bid = blockIdx.x;
    int b = bid & 7;                   // XCD-pinned batch
    int c = bid >> 3;
    int yp = c / SEGS_PER_ROW;
    int xseg = c - yp * SEGS_PER_ROW;
    int x = xseg * 256 + threadIdx.x;
    int ybase = yp * ROWS_PT;

    // interleaved low-res LDS tile: one ds_read_b128 yields {disp,s0,s1,s2}
    __shared__ float4 lds4[LROWS][LCOLS];
    int ylo = (int)((float)ybase * ((float)(H_IN - 1) / (float)(H_OUT - 1)));
    int xlo = (int)((float)(xseg * 256) * ((float)(W_IN - 1) / (float)(W_OUT - 1)));
    if (threadIdx.x < LROWS * LCOLS) {
        int row = threadIdx.x / LCOLS;
        int col = threadIdx.x - row * LCOLS;
        int gy = min(ylo + row, H_IN - 1);
        int gx = min(xlo + col, W_IN - 1);
        int gi = gy * W_IN + gx;
        const float* dp = disp + b * HW_IN;
        const float* sp = scene + b * (CH * HW_IN);
        float4 v;
        v.x = dp[gi];
        v.y = sp[gi];
        v.z = sp[HW_IN + gi];
        v.w = sp[2 * HW_IN + gi];
        lds4[row][col] = v;
    }
    __syncthreads();

    float sy = (float)H_OUT / aug[b * 2 + 0];
    float sxs = (float)W_OUT / aug[b * 2 + 1];
    float fx = intrin[b * 9 + 0] * sxs;
    float fy = intrin[b * 9 + 4] * sy;
    float cx = intrin[b * 9 + 2] * sxs;
    float cy = intrin[b * 9 + 5] * sy;
    float inv_fx = 1.0f / fx;
    float inv_fy = 1.0f / fy;

    float xsrc = (float)x * ((float)(W_IN - 1) / (float)(W_OUT - 1));
    int x0 = (int)xsrc;
    float wx = xsrc - (float)x0;
    int lx = x0 - xlo;

    float g00[ROWS_PT], g01[ROWS_PT], g10[ROWS_PT], g11[ROWS_PT];
    int rb0[ROWS_PT], rb1[ROWS_PT];
    bool rc[ROWS_PT], lc[ROWS_PT];   // used by planar fallback only

    #pragma unroll
    for (int r = 0; r < ROWS_PT; ++r) {
        int y = ybase + r;
        float ysrc = (float)y * ((float)(H_IN - 1) / (float)(H_OUT - 1));
        int y0 = (int)ysrc;
        float wy = ysrc - (float)y0;
        int ly = y0 - ylo;

        // 4 x ds_read_b128: all four surfaces per tap
        float4 t00 = lds4[ly][lx];
        float4 t01 = lds4[ly][lx + 1];
        float4 t10 = lds4[ly + 1][lx];
        float4 t11 = lds4[ly + 1][lx + 1];

        float w00 = (1.0f - wy) * (1.0f - wx);
        float w01 = (1.0f - wy) * wx;
        float w10 = wy * (1.0f - wx);
        float w11 = wy * wx;

        float dval = w00 * t00.x + w01 * t01.x + w10 * t10.x + w11 * t11.x;
        float sc0  = w00 * t00.y + w01 * t01.y + w10 * t10.y + w11 * t11.y;
        float sc1  = w00 * t00.z + w01 * t01.z + w10 * t10.z + w11 * t11.z;
        float sc2  = w00 * t00.w + w01 * t01.w + w10 * t10.w + w11 * t11.w;

        float disp_full = dval * (float)W_OUT;
        float depth = fminf(fmaxf(fx * 0.54f / (disp_full + 1e-8f), 0.001f), 80.0f);

        float X = ((float)x - cx) * inv_fx * depth + sc0;
        float Y = ((float)y - cy) * inv_fy * depth + sc1;
        float Z = depth + sc2;
        float u = fx * X + cx * Z;
        float v = fy * Y + cy * Z;
        float rw = 1.0f / (Z + 1e-8f);
        // normalize round-trip elided: gx == coord_x, gy == coord_y exactly
        float gx = u * rw;
        float gy = v * rw;

        float gx0f = floorf(gx), gy0f = floorf(gy);
        float fwx = gx - gx0f, fwy = gy - gy0f;
        int ix0 = (int)gx0f, iy0 = (int)gy0f;
        int ix1 = ix0 + 1, iy1 = iy0 + 1;
        bool vx0 = (ix0 >= 0) && (ix0 <= W_OUT - 1);
        bool vx1 = (ix1 >= 0) && (ix1 <= W_OUT - 1);
        bool vy0 = (iy0 >= 0) && (iy0 <= H_OUT - 1);
        bool vy1 = (iy1 >= 0) && (iy1 <= H_OUT - 1);
        int cy0 = min(max(iy0, 0), H_OUT - 1);
        int cy1 = min(max(iy1, 0), H_OUT - 1);
        g00[r] = (1.0f - fwy) * (1.0f - fwx) * ((vx0 && vy0) ? 1.0f : 0.0f);
        g01[r] = (1.0f - fwy) * fwx * ((vx1 && vy0) ? 1.0f : 0.0f);
        g10[r] = fwy * (1.0f - fwx) * ((vx0 && vy1) ? 1.0f : 0.0f);
        g11[r] = fwy * fwx * ((vx1 && vy1) ? 1.0f : 0.0f);

        if constexpr (PACKED) {
            // base column in [-1, 1279]: x0 tap = w[0..1], x1 tap = w[2..3] always
            int bx = min(max(ix0, -1), W_OUT - 1);
            rb0[r] = ((b * H_OUT + cy0) * PSTRIDE + bx);
            rb1[r] = ((b * H_OUT + cy1) * PSTRIDE + bx);
        } else {
            int cx0 = min(max(ix0, 0), W_OUT - 1);
            int cx1 = min(max(ix1, 0), W_OUT - 1);
            int xbi = min(cx0, W_OUT - 2);
            rc[r] = (cx0 != xbi);
            lc[r] = (cx1 == xbi);
            rb0[r] = cy0 * W_OUT + xbi;
            rb1[r] = cy1 * W_OUT + xbi;
        }
    }

    float res[ROWS_PT][CH];
    if constexpr (PACKED) {
        const __half* pd = pk + 4;
        #pragma unroll
        for (int r = 0; r < ROWS_PT; ++r) {
            h8 L0 = *reinterpret_cast<const h8*>(pd + (size_t)rb0[r] * 4);
            h8 L1 = *reinterpret_cast<const h8*>(pd + (size_t)rb1[r] * 4);
            __half2 h0a = *reinterpret_cast<__half2*>(&L0.w[0]);  // x0: c0,c1 (row y0)
            __half2 h0b = *reinterpret_cast<__half2*>(&L0.w[1]);  // x0: c2
            __half2 h1a = *reinterpret_cast<__half2*>(&L0.w[2]);  // x1: c0,c1
            __half2 h1b = *reinterpret_cast<__half2*>(&L0.w[3]);
            __half2 k0a = *reinterpret_cast<__half2*>(&L1.w[0]);  // row y1
            __half2 k0b = *reinterpret_cast<__half2*>(&L1.w[1]);
            __half2 k1a = *reinterpret_cast<__half2*>(&L1.w[2]);
            __half2 k1b = *reinterpret_cast<__half2*>(&L1.w[3]);
            res[r][0] = g00[r] * __low2float(h0a) + g01[r] * __low2float(h1a)
                      + g10[r] * __low2float(k0a) + g11[r] * __low2float(k1a);
            res[r][1] = g00[r] * __high2float(h0a) + g01[r] * __high2float(h1a)
                      + g10[r] * __high2float(k0a) + g11[r] * __high2float(k1a);
            res[r][2] = g00[r] * __low2float(h0b) + g01[r] * __low2float(h1b)
                      + g10[r] * __low2float(k0b) + g11[r] * __low2float(k1b);
        }
    } else {
        const float* ib = image + (size_t)b * (CH * HW_OUT);
        const float* im0 = ib;
        const float* im1 = ib + HW_OUT;
        const float* im2 = ib + 2 * HW_OUT;
        #pragma unroll
        for (int r = 0; r < ROWS_PT; ++r) {
            f2 P0 = *(const f2*)(im0 + rb0[r]); f2 P1 = *(const f2*)(im0 + rb1[r]);
            f2 Q0 = *(const f2*)(im1 + rb0[r]); f2 Q1 = *(const f2*)(im1 + rb1[r]);
            f2 T0 = *(const f2*)(im2 + rb0[r]); f2 T1 = *(const f2*)(im2 + rb1[r]);
            float p00 = rc[r] ? P0.y : P0.x, p01 = lc[r] ? P0.x : P0.y;
            float p10 = rc[r] ? P1.y : P1.x, p11 = lc[r] ? P1.x : P1.y;
            float q00 = rc[r] ? Q0.y : Q0.x, q01 = lc[r] ? Q0.x : Q0.y;
            float q10 = rc[r] ? Q1.y : Q1.x, q11 = lc[r] ? Q1.x : Q1.y;
            float t00 = rc[r] ? T0.y : T0.x, t01 = lc[r] ? T0.x : T0.y;
            float t10 = rc[r] ? T1.y : T1.x, t11 = lc[r] ? T1.x : T1.y;
            res[r][0] = g00[r] * p00 + g01[r] * p01 + g10[r] * p10 + g11[r] * p11;
            res[r][1] = g00[r] * q00 + g01[r] * q01 + g10[r] * q10 + g11[r] * q11;
            res[r][2] = g00[r] * t00 + g01[r] * t01 + g10[r] * t10 + g11[r] * t11;
        }
    }

    float* ob = out + (size_t)b * (CH * HW_OUT);
    #pragma unroll
    for (int r = 0; r < ROWS_PT; ++r) {
        int op = (ybase + r) * W_OUT + x;
        __builtin_nontemporal_store(res[r][0], ob + op);
        __builtin_nontemporal_store(res[r][1], ob + HW_OUT + op);
        __builtin_nontemporal_store(res[r][2], ob + 2 * HW_OUT + op);
    }
}

extern "C" void kernel_launch(void* const* d_in, const int* in_sizes, int n_in,
                              void* d_out, int out_size, void* d_ws, size_t ws_size,
                              hipStream_t stream) {
    const float* image  = (const float*)d_in[0];
    const float* disp   = (const float*)d_in[1];
    const float* scene  = (const float*)d_in[2];
    const float* intrin = (const float*)d_in[3];
    const float* aug    = (const float*)d_in[4];
    float* out = (float*)d_out;

    const int grid = BATCH * CHUNKS_PER_B;  // 7680 blocks

    if (ws_size >= PK_BYTES) {
        __half* pk = (__half*)d_ws;
        pack_kernel<<<BATCH * HW_OUT / 256, 256, 0, stream>>>(image, pk);
        warp_sceneflow_kernel<true><<<grid, 256, 0, stream>>>(
            image, pk, disp, scene, intrin, aug, out);
    } else {
        warp_sceneflow_kernel<false><<<grid, 256, 0, stream>>>(
            image, nullptr, disp, scene, intrin, aug, out);
    }
}